// Round 1
// baseline (255.714 us; speedup 1.0000x reference)
//
#include <hip/hip_runtime.h>

// ModulatedDeformConv (DCNv2) fused kernel — fp32 baseline.
// B=8, Cin=Cout=128, H=W=Ho=Wo=64, kh=kw=3, stride=1, pad=1, dil=1.
//
// Structure: grid = 512 blocks = (b, ho). Each block computes out[b, :, ho, :]
// (128 co x 64 wo). Loop over k (9) x ci-chunk (2 of 64):
//   - stage sampled cols s[64ci][64p] in LDS (bilinear*mask, table-driven)
//   - stage weight tile w[64ci][128co] in LDS (from pre-transposed ws copy)
//   - 8co x 4p register tile per thread: 3x ds_read_b128 per 32 v_fma_f32.

constexpr int CIN = 128, COUT = 128, H = 64, W = 64, KK = 9;
constexpr int HW = H * W;
constexpr int WSTR = 128;  // w_tile row stride (floats)

__global__ __launch_bounds__(256) void wtrans_kernel(
    const float* __restrict__ w, float* __restrict__ wt) {
  int i = blockIdx.x * 256 + threadIdx.x;
  if (i < COUT * CIN * KK) {
    const int k  = i % KK;
    const int ci = (i / KK) % CIN;
    const int co = i / (KK * CIN);
    wt[(k * CIN + ci) * COUT + co] = w[i];
  }
}

template <bool USE_WT>
__global__ __launch_bounds__(256) void dcn_kernel(
    const float* __restrict__ input,
    const float* __restrict__ offset,
    const float* __restrict__ mask,
    const float* __restrict__ weight,  // USE_WT: [k][ci][co]; else [co][ci][k]
    const float* __restrict__ bias,
    float* __restrict__ out) {
  __shared__ short4 pos_o[KK * 64];   // 4 clamped flat offsets per (k,p)
  __shared__ float4 pos_w[KK * 64];   // 4 bilinear*mask*valid weights
  __shared__ float  s_tile[64 * 64];  // [ci_local][p]
  __shared__ float  w_tile[64 * WSTR];// [ci_local][co]

  const int b   = blockIdx.x >> 6;
  const int ho  = blockIdx.x & 63;
  const int tid = threadIdx.x;

  // ---- Phase A: per-(k,p) bilinear tables (576 entries) ----
  for (int idx = tid; idx < KK * 64; idx += 256) {
    const int k = idx >> 6, p = idx & 63;
    const int ky = k / 3, kx = k - 3 * ky;
    const float py = (float)(ho - 1 + ky) +
                     offset[((b * 18 + 2 * k) * 64 + ho) * 64 + p];
    const float px = (float)(p - 1 + kx) +
                     offset[((b * 18 + 2 * k + 1) * 64 + ho) * 64 + p];
    const float m = mask[((b * 9 + k) * 64 + ho) * 64 + p];
    const float y0f = floorf(py), x0f = floorf(px);
    const int y0 = (int)y0f, x0 = (int)x0f;
    const float ly = py - y0f, lx = px - x0f;
    const float hy = 1.f - ly, hx = 1.f - lx;
    const bool vy0 = (y0 >= 0) && (y0 < H);
    const bool vy1 = (y0 + 1 >= 0) && (y0 + 1 < H);
    const bool vx0 = (x0 >= 0) && (x0 < W);
    const bool vx1 = (x0 + 1 >= 0) && (x0 + 1 < W);
    const int cy0 = min(max(y0, 0), H - 1), cy1 = min(max(y0 + 1, 0), H - 1);
    const int cx0 = min(max(x0, 0), W - 1), cx1 = min(max(x0 + 1, 0), W - 1);
    pos_o[idx] = make_short4((short)(cy0 * W + cx0), (short)(cy0 * W + cx1),
                             (short)(cy1 * W + cx0), (short)(cy1 * W + cx1));
    pos_w[idx] = make_float4((vy0 && vx0) ? hy * hx * m : 0.f,
                             (vy0 && vx1) ? hy * lx * m : 0.f,
                             (vy1 && vx0) ? ly * hx * m : 0.f,
                             (vy1 && vx1) ? ly * lx * m : 0.f);
  }

  const int cog = tid >> 4;  // 0..15 -> co block of 8
  const int pg  = tid & 15;  // 0..15 -> p block of 4
  float acc[8][4];
#pragma unroll
  for (int j = 0; j < 8; ++j)
#pragma unroll
    for (int q = 0; q < 4; ++q) acc[j][q] = 0.f;

  const float* inp_b = input + (size_t)b * CIN * HW;

  for (int k = 0; k < KK; ++k) {
    for (int cc = 0; cc < 2; ++cc) {
      __syncthreads();  // covers Phase A on first iter; tile reuse after
      // ---- stage sampled tile: s[ci_local][p] ----
      for (int i = tid; i < 64 * 64; i += 256) {
        const int cil = i >> 6, p = i & 63;
        const float* plane = inp_b + (cc * 64 + cil) * HW;
        const short4 o = pos_o[k * 64 + p];
        const float4 w = pos_w[k * 64 + p];
        s_tile[i] = w.x * plane[(int)o.x] + w.y * plane[(int)o.y] +
                    w.z * plane[(int)o.z] + w.w * plane[(int)o.w];
      }
      // ---- stage weight tile: w_tile[ci_local][co] ----
      if (USE_WT) {
        for (int i = tid; i < 64 * 128; i += 256) {
          const int cil = i >> 7, co = i & 127;  // co fast: coalesced global
          w_tile[cil * WSTR + co] = weight[(k * CIN + cc * 64 + cil) * COUT + co];
        }
      } else {
        for (int i = tid; i < 64 * 128; i += 256) {
          const int cil = i & 63, co = i >> 6;   // ci fast: least-bad global
          w_tile[cil * WSTR + co] = weight[(co * CIN + cc * 64 + cil) * KK + k];
        }
      }
      __syncthreads();
      // ---- 8co x 4p register-tile FMA over 64 ci ----
#pragma unroll 8
      for (int cil = 0; cil < 64; ++cil) {
        const float4 sv = *(const float4*)&s_tile[cil * 64 + (pg << 2)];
        const float4 wa = *(const float4*)&w_tile[cil * WSTR + (cog << 3)];
        const float4 wb = *(const float4*)&w_tile[cil * WSTR + (cog << 3) + 4];
        const float s4[4] = {sv.x, sv.y, sv.z, sv.w};
        const float w8[8] = {wa.x, wa.y, wa.z, wa.w, wb.x, wb.y, wb.z, wb.w};
#pragma unroll
        for (int j = 0; j < 8; ++j)
#pragma unroll
          for (int q = 0; q < 4; ++q)
            acc[j][q] = fmaf(w8[j], s4[q], acc[j][q]);
      }
    }
  }

  // ---- epilogue: add bias, store float4 ----
  float* outp = out + (size_t)b * COUT * HW + ho * W;
#pragma unroll
  for (int j = 0; j < 8; ++j) {
    const int co = (cog << 3) + j;
    const float bb = bias[co];
    float4 o = make_float4(acc[j][0] + bb, acc[j][1] + bb, acc[j][2] + bb,
                           acc[j][3] + bb);
    *(float4*)&outp[co * HW + (pg << 2)] = o;
  }
}

extern "C" void kernel_launch(void* const* d_in, const int* in_sizes, int n_in,
                              void* d_out, int out_size, void* d_ws,
                              size_t ws_size, hipStream_t stream) {
  const float* input  = (const float*)d_in[0];
  const float* offset = (const float*)d_in[1];
  const float* mask   = (const float*)d_in[2];
  const float* weight = (const float*)d_in[3];
  const float* bias   = (const float*)d_in[4];
  float* out = (float*)d_out;

  const size_t wt_bytes = (size_t)COUT * CIN * KK * sizeof(float);
  if (ws_size >= wt_bytes) {
    float* wt = (float*)d_ws;
    hipLaunchKernelGGL(wtrans_kernel, dim3((COUT * CIN * KK + 255) / 256),
                       dim3(256), 0, stream, weight, wt);
    hipLaunchKernelGGL((dcn_kernel<true>), dim3(512), dim3(256), 0, stream,
                       input, offset, mask, wt, bias, out);
  } else {
    hipLaunchKernelGGL((dcn_kernel<false>), dim3(512), dim3(256), 0, stream,
                       input, offset, mask, weight, bias, out);
  }
}

// Round 2
// 175.828 us; speedup vs baseline: 1.4543x; 1.4543x over previous
//
#include <hip/hip_runtime.h>

// DCNv2 fused: bilinear-sample -> LDS bf16 hi/lo tiles -> MFMA (bf16x3 split GEMM).
// B=8, Cin=Cout=128, H=W=Ho=Wo=64, kh=kw=3, stride=1, pad=1, dil=1.
// grid 512 = (ho, b) with b = blockIdx&7 (XCD swizzle: batch b -> XCD b, input[b]
// fits 4MB L2). 256 threads = 4 waves; each wave computes 32co x 64p via
// 2x4 grid of 16x16x32 bf16 MFMA tiles, 3 passes (hh, hl, lh) per K-step.
// Weights pre-split to fragment-ordered bf16 hi/lo in d_ws (A-frags read
// straight from global/L2 -> DS pipe only carries s-tile writes + B-frags).

constexpr int CIN = 128, COUT = 128, H = 64, W = 64, KK = 9;
constexpr int HW = H * W;
constexpr int SROW = 72;  // s_tile row stride in bf16 (16B-aligned, bank-spread)

typedef __attribute__((ext_vector_type(8))) short short8;
typedef __attribute__((ext_vector_type(4))) float float4v;

static __device__ __forceinline__ unsigned short f32_to_bf16_rne(float f) {
  unsigned u = __float_as_uint(f);
  return (unsigned short)((u + 0x7FFFu + ((u >> 16) & 1u)) >> 16);
}
static __device__ __forceinline__ float bf16_to_f32(unsigned short h) {
  return __uint_as_float(((unsigned)h) << 16);
}

struct __attribute__((packed, aligned(4))) f2u { float x, y; };

// ---- prep: weight[co][ci][k] -> fragment-ordered bf16 hi/lo planes ----
// layout: [kt=(k*2+cc)*2+step][c16][lane][j]  (512 bf16 per (kt,c16) block)
// value = w[co = c16*16 + (lane&15)][ci = cc*64+step*32+(lane>>4)*8+j][k]
__global__ __launch_bounds__(256) void wprep_kernel(
    const float* __restrict__ w, unsigned short* __restrict__ wt_hi,
    unsigned short* __restrict__ wt_lo) {
  const int t = blockIdx.x * 256 + threadIdx.x;
  if (t >= 36 * 8 * 64) return;
  const int lane = t & 63;
  const int c16 = (t >> 6) & 7;
  const int kt = t >> 9;                  // 0..35
  const int step = kt & 1, cc = (kt >> 1) & 1, k = kt >> 2;
  const int co = c16 * 16 + (lane & 15);
  const int ci0 = cc * 64 + step * 32 + (lane >> 4) * 8;
  unsigned hw_[4], lw_[4];
#pragma unroll
  for (int jj = 0; jj < 4; ++jj) {
    unsigned short h2[2], l2[2];
#pragma unroll
    for (int e = 0; e < 2; ++e) {
      const float v = w[(co * CIN + ci0 + jj * 2 + e) * KK + k];
      const unsigned short h = f32_to_bf16_rne(v);
      h2[e] = h;
      l2[e] = f32_to_bf16_rne(v - bf16_to_f32(h));
    }
    hw_[jj] = (unsigned)h2[0] | ((unsigned)h2[1] << 16);
    lw_[jj] = (unsigned)l2[0] | ((unsigned)l2[1] << 16);
  }
  *(uint4*)(wt_hi + (size_t)t * 8) = make_uint4(hw_[0], hw_[1], hw_[2], hw_[3]);
  *(uint4*)(wt_lo + (size_t)t * 8) = make_uint4(lw_[0], lw_[1], lw_[2], lw_[3]);
}

__global__ __launch_bounds__(256) void dcn_mfma_kernel(
    const float* __restrict__ input,
    const float* __restrict__ offset,
    const float* __restrict__ mask,
    const unsigned short* __restrict__ wt_hi,
    const unsigned short* __restrict__ wt_lo,
    const float* __restrict__ bias,
    float* __restrict__ out) {
  __shared__ int4 pos_i[KK * 64];            // addr0, addr1, s0, s1
  __shared__ float4 pos_w[KK * 64];          // 4 bilinear*mask*valid weights
  __shared__ unsigned short s_hi[64 * SROW]; // [p][ci] bf16 hi
  __shared__ unsigned short s_lo[64 * SROW]; // [p][ci] bf16 lo

  const int b = blockIdx.x & 7;    // XCD swizzle: same batch -> same XCD L2
  const int ho = blockIdx.x >> 3;
  const int tid = threadIdx.x;

  // ---- Phase A: per-(k,p) bilinear tables ----
  for (int idx = tid; idx < KK * 64; idx += 256) {
    const int k = idx >> 6, p = idx & 63;
    const int ky = k / 3, kx = k - 3 * ky;
    const float py = (float)(ho - 1 + ky) +
                     offset[((b * 18 + 2 * k) * 64 + ho) * 64 + p];
    const float px = (float)(p - 1 + kx) +
                     offset[((b * 18 + 2 * k + 1) * 64 + ho) * 64 + p];
    const float m = mask[((b * 9 + k) * 64 + ho) * 64 + p];
    const float y0f = floorf(py), x0f = floorf(px);
    const int y0 = (int)y0f, x0 = (int)x0f;
    const float ly = py - y0f, lx = px - x0f;
    const float hy = 1.f - ly, hx = 1.f - lx;
    const bool vy0 = (y0 >= 0) && (y0 < H);
    const bool vy1 = (y0 + 1 >= 0) && (y0 + 1 < H);
    const bool vx0 = (x0 >= 0) && (x0 < W);
    const bool vx1 = (x0 + 1 >= 0) && (x0 + 1 < W);
    const int cy0 = min(max(y0, 0), H - 1), cy1 = min(max(y0 + 1, 0), H - 1);
    const int bx = min(max(x0, 0), W - 2);  // dwordx2 base column
    const int s0 = min(max(x0 - bx, 0), 1);
    const int s1 = min(max(x0 + 1 - bx, 0), 1);
    pos_i[idx] = make_int4(cy0 * W + bx, cy1 * W + bx, s0, s1);
    pos_w[idx] = make_float4((vy0 && vx0) ? hy * hx * m : 0.f,
                             (vy0 && vx1) ? hy * lx * m : 0.f,
                             (vy1 && vx0) ? ly * hx * m : 0.f,
                             (vy1 && vx1) ? ly * lx * m : 0.f);
  }
  __syncthreads();

  const int wave = tid >> 6;
  const int lane = tid & 63;
  const int quad = lane >> 4;
  const int l15 = lane & 15;
  const int p = tid & 63;           // staging: p per thread
  const int ci_base = wave * 16;    // staging: 16 ci per thread

  float4v acc[2][4];
#pragma unroll
  for (int s = 0; s < 2; ++s)
#pragma unroll
    for (int n = 0; n < 4; ++n) acc[s][n] = (float4v)(0.f);

  const float* inp_b = input + (size_t)b * CIN * HW;

  for (int k = 0; k < KK; ++k) {
    const int4 P = pos_i[(k << 6) | p];
    const float4 Wq = pos_w[(k << 6) | p];
    for (int cc = 0; cc < 2; ++cc) {
      // ---- stage s tile: 16 ci x 1 p per thread, dwordx2 paired-x loads ----
      const float* plane0 = inp_b + (size_t)(cc * 64 + ci_base) * HW;
#pragma unroll
      for (int u = 0; u < 2; ++u) {
        unsigned hw_[4], lw_[4];
#pragma unroll
        for (int jj = 0; jj < 4; ++jj) {
          unsigned short h2[2], l2[2];
#pragma unroll
          for (int e = 0; e < 2; ++e) {
            const float* pl = plane0 + (size_t)(u * 8 + jj * 2 + e) * HW;
            const f2u r0 = *(const f2u*)(pl + P.x);
            const f2u r1 = *(const f2u*)(pl + P.y);
            const float v00 = P.z ? r0.y : r0.x;
            const float v01 = P.w ? r0.y : r0.x;
            const float v10 = P.z ? r1.y : r1.x;
            const float v11 = P.w ? r1.y : r1.x;
            const float v = Wq.x * v00 + Wq.y * v01 + Wq.z * v10 + Wq.w * v11;
            const unsigned short h = f32_to_bf16_rne(v);
            h2[e] = h;
            l2[e] = f32_to_bf16_rne(v - bf16_to_f32(h));
          }
          hw_[jj] = (unsigned)h2[0] | ((unsigned)h2[1] << 16);
          lw_[jj] = (unsigned)l2[0] | ((unsigned)l2[1] << 16);
        }
        const int so = p * SROW + ci_base + u * 8;
        *(uint4*)&s_hi[so] = make_uint4(hw_[0], hw_[1], hw_[2], hw_[3]);
        *(uint4*)&s_lo[so] = make_uint4(lw_[0], lw_[1], lw_[2], lw_[3]);
      }
      __syncthreads();

      // ---- MFMA phase: A-frags from global (L2), B-frags from LDS ----
      const int kt2 = (k * 2 + cc) * 2;
#pragma unroll
      for (int step = 0; step < 2; ++step) {
        const size_t fb =
            ((size_t)(kt2 + step) * 8 + wave * 2) * 512 + (size_t)lane * 8;
        short8 ah[2], al[2];
        ah[0] = *(const short8*)(wt_hi + fb);
        al[0] = *(const short8*)(wt_lo + fb);
        ah[1] = *(const short8*)(wt_hi + fb + 512);
        al[1] = *(const short8*)(wt_lo + fb + 512);
        short8 bh[4], bl[4];
#pragma unroll
        for (int ns = 0; ns < 4; ++ns) {
          const int so = (ns * 16 + l15) * SROW + step * 32 + quad * 8;
          bh[ns] = *(const short8*)&s_hi[so];
          bl[ns] = *(const short8*)&s_lo[so];
        }
#pragma unroll
        for (int sub = 0; sub < 2; ++sub)
#pragma unroll
          for (int ns = 0; ns < 4; ++ns) {
            acc[sub][ns] = __builtin_amdgcn_mfma_f32_16x16x32_bf16(
                ah[sub], bh[ns], acc[sub][ns], 0, 0, 0);
            acc[sub][ns] = __builtin_amdgcn_mfma_f32_16x16x32_bf16(
                ah[sub], bl[ns], acc[sub][ns], 0, 0, 0);
            acc[sub][ns] = __builtin_amdgcn_mfma_f32_16x16x32_bf16(
                al[sub], bh[ns], acc[sub][ns], 0, 0, 0);
          }
      }
      __syncthreads();  // before next staging overwrites s tiles
    }
  }

  // ---- epilogue: C/D layout col=lane&15 (p), row=quad*4+reg (co) ----
#pragma unroll
  for (int sub = 0; sub < 2; ++sub) {
#pragma unroll
    for (int r = 0; r < 4; ++r) {
      const int co = wave * 32 + sub * 16 + quad * 4 + r;
      const float bb = bias[co];
      float* op = out + ((size_t)(b * COUT + co) * H + ho) * W;
#pragma unroll
      for (int ns = 0; ns < 4; ++ns)
        op[ns * 16 + l15] = acc[sub][ns][r] + bb;
    }
  }
}

// ---- fallback (ws too small): round-1 fp32 kernel, weight read in-place ----
__global__ __launch_bounds__(256) void dcn_fp32_kernel(
    const float* __restrict__ input, const float* __restrict__ offset,
    const float* __restrict__ mask, const float* __restrict__ weight,
    const float* __restrict__ bias, float* __restrict__ out) {
  __shared__ short4 pos_o[KK * 64];
  __shared__ float4 pos_w[KK * 64];
  __shared__ float s_tile[64 * 64];
  __shared__ float w_tile[64 * 128];
  const int b = blockIdx.x >> 6;
  const int ho = blockIdx.x & 63;
  const int tid = threadIdx.x;
  for (int idx = tid; idx < KK * 64; idx += 256) {
    const int k = idx >> 6, pp = idx & 63;
    const int ky = k / 3, kx = k - 3 * ky;
    const float py = (float)(ho - 1 + ky) +
                     offset[((b * 18 + 2 * k) * 64 + ho) * 64 + pp];
    const float px = (float)(pp - 1 + kx) +
                     offset[((b * 18 + 2 * k + 1) * 64 + ho) * 64 + pp];
    const float m = mask[((b * 9 + k) * 64 + ho) * 64 + pp];
    const float y0f = floorf(py), x0f = floorf(px);
    const int y0 = (int)y0f, x0 = (int)x0f;
    const float ly = py - y0f, lx = px - x0f;
    const float hy = 1.f - ly, hx = 1.f - lx;
    const bool vy0 = (y0 >= 0) && (y0 < H), vy1 = (y0 + 1 >= 0) && (y0 + 1 < H);
    const bool vx0 = (x0 >= 0) && (x0 < W), vx1 = (x0 + 1 >= 0) && (x0 + 1 < W);
    const int cy0 = min(max(y0, 0), H - 1), cy1 = min(max(y0 + 1, 0), H - 1);
    const int cx0 = min(max(x0, 0), W - 1), cx1 = min(max(x0 + 1, 0), W - 1);
    pos_o[idx] = make_short4((short)(cy0 * W + cx0), (short)(cy0 * W + cx1),
                             (short)(cy1 * W + cx0), (short)(cy1 * W + cx1));
    pos_w[idx] = make_float4((vy0 && vx0) ? hy * hx * m : 0.f,
                             (vy0 && vx1) ? hy * lx * m : 0.f,
                             (vy1 && vx0) ? ly * hx * m : 0.f,
                             (vy1 && vx1) ? ly * lx * m : 0.f);
  }
  const int cog = tid >> 4, pg = tid & 15;
  float acc[8][4];
#pragma unroll
  for (int j = 0; j < 8; ++j)
#pragma unroll
    for (int q = 0; q < 4; ++q) acc[j][q] = 0.f;
  const float* inp_b = input + (size_t)b * CIN * HW;
  for (int k = 0; k < KK; ++k) {
    for (int cc = 0; cc < 2; ++cc) {
      __syncthreads();
      for (int i = tid; i < 64 * 64; i += 256) {
        const int cil = i >> 6, pp = i & 63;
        const float* plane = inp_b + (size_t)(cc * 64 + cil) * HW;
        const short4 o = pos_o[k * 64 + pp];
        const float4 w = pos_w[k * 64 + pp];
        s_tile[i] = w.x * plane[(int)o.x] + w.y * plane[(int)o.y] +
                    w.z * plane[(int)o.z] + w.w * plane[(int)o.w];
      }
      for (int i = tid; i < 64 * 128; i += 256) {
        const int cil = i & 63, co = i >> 6;
        w_tile[cil * 128 + co] = weight[(co * CIN + cc * 64 + cil) * KK + k];
      }
      __syncthreads();
#pragma unroll 8
      for (int cil = 0; cil < 64; ++cil) {
        const float4 sv = *(const float4*)&s_tile[cil * 64 + (pg << 2)];
        const float4 wa = *(const float4*)&w_tile[cil * 128 + (cog << 3)];
        const float4 wb = *(const float4*)&w_tile[cil * 128 + (cog << 3) + 4];
        const float s4[4] = {sv.x, sv.y, sv.z, sv.w};
        const float w8[8] = {wa.x, wa.y, wa.z, wa.w, wb.x, wb.y, wb.z, wb.w};
#pragma unroll
        for (int j = 0; j < 8; ++j)
#pragma unroll
          for (int q = 0; q < 4; ++q) acc[j][q] = fmaf(w8[j], s4[q], acc[j][q]);
      }
    }
  }
  float* outp = out + (size_t)b * COUT * HW + ho * W;
#pragma unroll
  for (int j = 0; j < 8; ++j) {
    const int co = (cog << 3) + j;
    const float bb = bias[co];
    *(float4*)&outp[co * HW + (pg << 2)] =
        make_float4(acc[j][0] + bb, acc[j][1] + bb, acc[j][2] + bb,
                    acc[j][3] + bb);
  }
}

extern "C" void kernel_launch(void* const* d_in, const int* in_sizes, int n_in,
                              void* d_out, int out_size, void* d_ws,
                              size_t ws_size, hipStream_t stream) {
  const float* input = (const float*)d_in[0];
  const float* offset = (const float*)d_in[1];
  const float* mask = (const float*)d_in[2];
  const float* weight = (const float*)d_in[3];
  const float* bias = (const float*)d_in[4];
  float* out = (float*)d_out;

  const size_t plane_elems = 36 * 8 * 64 * 8;  // 147456 bf16 per hi/lo plane
  const size_t need = plane_elems * 2 * sizeof(unsigned short);
  if (ws_size >= need) {
    unsigned short* wt_hi = (unsigned short*)d_ws;
    unsigned short* wt_lo = wt_hi + plane_elems;
    hipLaunchKernelGGL(wprep_kernel, dim3(72), dim3(256), 0, stream, weight,
                       wt_hi, wt_lo);
    hipLaunchKernelGGL(dcn_mfma_kernel, dim3(512), dim3(256), 0, stream, input,
                       offset, mask, wt_hi, wt_lo, bias, out);
  } else {
    hipLaunchKernelGGL(dcn_fp32_kernel, dim3(512), dim3(256), 0, stream, input,
                       offset, mask, weight, bias, out);
  }
}

// Round 4
// 163.346 us; speedup vs baseline: 1.5655x; 1.0764x over previous
//
#include <hip/hip_runtime.h>

// DCNv2 fused, round 4: pipelined single-pass bf16 MFMA (round-3 design,
// epilogue UB fixed: accumulators are a real array, no address-of locals).
// B=8, Cin=Cout=128, H=W=Ho=Wo=64, kh=kw=3, stride=1, pad=1, dil=1.
// grid 1024 = (ph, ho, b): b = blk&7 (XCD swizzle), ho = (blk>>3)&63, ph = blk>>9.
// Each block: 128co x 32p tile. 256 threads = 4 waves; wave w: co 32w..32w+31,
// 2x2 grid of 16x16x32 bf16 MFMA tiles. Pipeline per (k,cc) step:
// convert+stage s_tile[buf] -> 1 barrier -> A-loads -> prefetch next gathers
// -> ds_read B + 8 MFMA. Double-buffered s_tile: no second barrier; no vmem
// in flight across the barrier. s_tile xor-swizzle kills b128 bank conflicts.

constexpr int CIN = 128, COUT = 128, H = 64, W = 64, KK = 9;
constexpr int HW = H * W;

typedef __attribute__((ext_vector_type(8))) short short8;
typedef __attribute__((ext_vector_type(4))) float float4v;

static __device__ __forceinline__ unsigned short f32_to_bf16_rne(float f) {
  unsigned u = __float_as_uint(f);
  return (unsigned short)((u + 0x7FFFu + ((u >> 16) & 1u)) >> 16);
}

// ---- weight prep: w[co][ci][k] fp32 -> bf16 A-fragments ----
// wt[kt = (k*2+cc)*2+step][c16][lane][j] ; value = w[co=c16*16+(lane&15)]
//                                             [ci=cc*64+step*32+(lane>>4)*8+j][k]
__global__ __launch_bounds__(256) void wprep_kernel(
    const float* __restrict__ w, unsigned short* __restrict__ wt) {
  const int t = blockIdx.x * 256 + threadIdx.x;
  if (t >= 36 * 8 * 64) return;
  const int lane = t & 63, c16 = (t >> 6) & 7, kt = t >> 9;
  const int step = kt & 1, cc = (kt >> 1) & 1, k = kt >> 2;
  const int co = c16 * 16 + (lane & 15);
  const int ci0 = cc * 64 + step * 32 + (lane >> 4) * 8;
  unsigned pk[4];
#pragma unroll
  for (int jj = 0; jj < 4; ++jj) {
    const unsigned short h0 =
        f32_to_bf16_rne(w[(co * CIN + ci0 + 2 * jj) * KK + k]);
    const unsigned short h1 =
        f32_to_bf16_rne(w[(co * CIN + ci0 + 2 * jj + 1) * KK + k]);
    pk[jj] = (unsigned)h0 | ((unsigned)h1 << 16);
  }
  *(uint4*)(wt + (size_t)t * 8) = make_uint4(pk[0], pk[1], pk[2], pk[3]);
}

__global__ __launch_bounds__(256) void dcn_mfma_kernel(
    const float* __restrict__ input, const float* __restrict__ offset,
    const float* __restrict__ mask, const unsigned short* __restrict__ wt,
    const float* __restrict__ bias, float* __restrict__ out) {
  __shared__ int2 pos_i[KK * 32];    // row0/row1 flat base index (col bx)
  __shared__ float4 pos_w[KK * 32];  // folded slot weights cA0,cB0,cA1,cB1
  __shared__ unsigned short s_hi[2][32 * 64];  // double-buffered, xor-swizzled

  const int b = blockIdx.x & 7;  // XCD swizzle: batch b -> XCD b (L2 locality)
  const int ho = (blockIdx.x >> 3) & 63;
  const int ph = (blockIdx.x >> 9) & 1;
  const int tid = threadIdx.x;

  // ---- Phase A: per-(k,p) tables; taps folded onto fixed slots (bx,bx+1) ----
  for (int idx = tid; idx < KK * 32; idx += 256) {
    const int k = idx >> 5, p = idx & 31;
    const int pg = ph * 32 + p;
    const int ky = k / 3, kx = k - 3 * ky;
    const float py = (float)(ho - 1 + ky) +
                     offset[((b * 18 + 2 * k) * 64 + ho) * 64 + pg];
    const float px = (float)(pg - 1 + kx) +
                     offset[((b * 18 + 2 * k + 1) * 64 + ho) * 64 + pg];
    const float m = mask[((b * 9 + k) * 64 + ho) * 64 + pg];
    const float y0f = floorf(py), x0f = floorf(px);
    const int y0 = (int)y0f, x0 = (int)x0f;
    const float ly = py - y0f, lx = px - x0f;
    const float hy = 1.f - ly, hx = 1.f - lx;
    const bool vy0 = (y0 >= 0) && (y0 < H);
    const bool vy1 = (y0 + 1 >= 0) && (y0 + 1 < H);
    const bool vx0 = (x0 >= 0) && (x0 < W);
    const bool vx1 = (x0 + 1 >= 0) && (x0 + 1 < W);
    const float w00 = (vy0 && vx0) ? hy * hx * m : 0.f;
    const float w01 = (vy0 && vx1) ? hy * lx * m : 0.f;
    const float w10 = (vy1 && vx0) ? ly * hx * m : 0.f;
    const float w11 = (vy1 && vx1) ? ly * lx * m : 0.f;
    const int cy0 = min(max(y0, 0), H - 1), cy1 = min(max(y0 + 1, 0), H - 1);
    const int bx = min(max(x0, 0), W - 2);
    const int s0 = min(max(x0 - bx, 0), 1);      // slot of tap x0
    const int s1 = min(max(x0 + 1 - bx, 0), 1);  // slot of tap x1
    // exact fold: invalid taps have weight 0, shared slots add a zero term
    const float cA0 = (s0 == 0 ? w00 : 0.f) + (s1 == 0 ? w01 : 0.f);
    const float cB0 = (s0 == 1 ? w00 : 0.f) + (s1 == 1 ? w01 : 0.f);
    const float cA1 = (s0 == 0 ? w10 : 0.f) + (s1 == 0 ? w11 : 0.f);
    const float cB1 = (s0 == 1 ? w10 : 0.f) + (s1 == 1 ? w11 : 0.f);
    pos_i[idx] = make_int2(cy0 * W + bx, cy1 * W + bx);
    pos_w[idx] = make_float4(cA0, cB0, cA1, cB1);
  }
  __syncthreads();

  const int wave = tid >> 6, lane = tid & 63;
  const int quad = lane >> 4, l15 = lane & 15;
  const int p_loc = tid & 31;                // staged row (p within tile)
  const int cig = tid >> 5;                  // ci granule 0..7
  const int sw8 = (cig ^ (p_loc & 7)) * 8;   // xor-swizzled granule offset

  float4v acc[2][2];  // [sub = co 16-block][ns = p 16-block]
#pragma unroll
  for (int s = 0; s < 2; ++s)
#pragma unroll
    for (int n = 0; n < 2; ++n) acc[s][n] = (float4v)(0.f);

  const float* pbase = input + ((size_t)b * CIN + cig * 8) * HW;

  int2 P = pos_i[p_loc];
  float4 Wc = pos_w[p_loc];
  float g[8][4];  // in-flight gathers: [plane][v00,v01,v10,v11]

  // prologue: issue gathers for t=0 (k=0, cc=0)
#pragma unroll
  for (int j = 0; j < 8; ++j) {
    const float* pl = pbase + (size_t)j * HW;
    g[j][0] = pl[P.x];
    g[j][1] = pl[P.x + 1];
    g[j][2] = pl[P.y];
    g[j][3] = pl[P.y + 1];
  }

  for (int t = 0; t < 18; ++t) {  // t = k*2 + cc
    const int buf = t & 1;
    // ---- convert + stage (vmcnt wait on g use) ----
    unsigned pk[4];
#pragma unroll
    for (int jj = 0; jj < 4; ++jj) {
      const float v0 = Wc.x * g[2 * jj][0] + Wc.y * g[2 * jj][1] +
                       Wc.z * g[2 * jj][2] + Wc.w * g[2 * jj][3];
      const float v1 = Wc.x * g[2 * jj + 1][0] + Wc.y * g[2 * jj + 1][1] +
                       Wc.z * g[2 * jj + 1][2] + Wc.w * g[2 * jj + 1][3];
      pk[jj] =
          (unsigned)f32_to_bf16_rne(v0) | ((unsigned)f32_to_bf16_rne(v1) << 16);
    }
    *(uint4*)&s_hi[buf][p_loc * 64 + sw8] =
        make_uint4(pk[0], pk[1], pk[2], pk[3]);
    __syncthreads();  // no vmem in flight here: cheap drain

    // ---- A-frag loads FIRST (so MFMA's vmcnt wait doesn't drain gathers) ----
    short8 A[2][2];
#pragma unroll
    for (int step = 0; step < 2; ++step) {
      const size_t ab =
          ((size_t)(t * 2 + step) * 8 + wave * 2) * 512 + (size_t)lane * 8;
      A[step][0] = *(const short8*)(wt + ab);
      A[step][1] = *(const short8*)(wt + ab + 512);
    }

    // ---- prefetch next step's gathers (latency hidden by MFMA phase) ----
    if (t < 17) {
      const int t1 = t + 1, k1 = t1 >> 1, cc1 = t1 & 1;
      if (cc1 == 0) {
        P = pos_i[k1 * 32 + p_loc];
        Wc = pos_w[k1 * 32 + p_loc];
      }
      const float* pb = pbase + (size_t)(cc1 * 64) * HW;
#pragma unroll
      for (int j = 0; j < 8; ++j) {
        const float* pl = pb + (size_t)j * HW;
        g[j][0] = pl[P.x];
        g[j][1] = pl[P.x + 1];
        g[j][2] = pl[P.y];
        g[j][3] = pl[P.y + 1];
      }
    }

    // ---- B ds_reads + 8 MFMA ----
#pragma unroll
    for (int step = 0; step < 2; ++step) {
      const int gsl = ((step * 4 + quad) ^ (l15 & 7)) * 8;
      const short8 b0 = *(const short8*)&s_hi[buf][l15 * 64 + gsl];
      const short8 b1 = *(const short8*)&s_hi[buf][(16 + l15) * 64 + gsl];
      acc[0][0] =
          __builtin_amdgcn_mfma_f32_16x16x32_bf16(A[step][0], b0, acc[0][0], 0, 0, 0);
      acc[0][1] =
          __builtin_amdgcn_mfma_f32_16x16x32_bf16(A[step][0], b1, acc[0][1], 0, 0, 0);
      acc[1][0] =
          __builtin_amdgcn_mfma_f32_16x16x32_bf16(A[step][1], b0, acc[1][0], 0, 0, 0);
      acc[1][1] =
          __builtin_amdgcn_mfma_f32_16x16x32_bf16(A[step][1], b1, acc[1][1], 0, 0, 0);
    }
  }

  // ---- epilogue: C/D layout col(N=p)=lane&15, row(M=co)=quad*4+reg ----
#pragma unroll
  for (int sub = 0; sub < 2; ++sub) {
#pragma unroll
    for (int r = 0; r < 4; ++r) {
      const int co = wave * 32 + sub * 16 + quad * 4 + r;
      const float bb = bias[co];
      float* op = out + ((size_t)(b * COUT + co) * H + ho) * W + ph * 32;
      op[l15] = acc[sub][0][r] + bb;       // ns=0
      op[16 + l15] = acc[sub][1][r] + bb;  // ns=1
    }
  }
}

// ---- fallback (ws too small): round-1 fp32 kernel ----
__global__ __launch_bounds__(256) void dcn_fp32_kernel(
    const float* __restrict__ input, const float* __restrict__ offset,
    const float* __restrict__ mask, const float* __restrict__ weight,
    const float* __restrict__ bias, float* __restrict__ out) {
  __shared__ short4 pos_o[KK * 64];
  __shared__ float4 pos_w[KK * 64];
  __shared__ float s_tile[64 * 64];
  __shared__ float w_tile[64 * 128];
  const int b = blockIdx.x >> 6;
  const int ho = blockIdx.x & 63;
  const int tid = threadIdx.x;
  for (int idx = tid; idx < KK * 64; idx += 256) {
    const int k = idx >> 6, pp = idx & 63;
    const int ky = k / 3, kx = k - 3 * ky;
    const float py = (float)(ho - 1 + ky) +
                     offset[((b * 18 + 2 * k) * 64 + ho) * 64 + pp];
    const float px = (float)(pp - 1 + kx) +
                     offset[((b * 18 + 2 * k + 1) * 64 + ho) * 64 + pp];
    const float m = mask[((b * 9 + k) * 64 + ho) * 64 + pp];
    const float y0f = floorf(py), x0f = floorf(px);
    const int y0 = (int)y0f, x0 = (int)x0f;
    const float ly = py - y0f, lx = px - x0f;
    const float hy = 1.f - ly, hx = 1.f - lx;
    const bool vy0 = (y0 >= 0) && (y0 < H), vy1 = (y0 + 1 >= 0) && (y0 + 1 < H);
    const bool vx0 = (x0 >= 0) && (x0 < W), vx1 = (x0 + 1 >= 0) && (x0 + 1 < W);
    const int cy0 = min(max(y0, 0), H - 1), cy1 = min(max(y0 + 1, 0), H - 1);
    const int cx0 = min(max(x0, 0), W - 1), cx1 = min(max(x0 + 1, 0), W - 1);
    pos_o[idx] = make_short4((short)(cy0 * W + cx0), (short)(cy0 * W + cx1),
                             (short)(cy1 * W + cx0), (short)(cy1 * W + cx1));
    pos_w[idx] = make_float4((vy0 && vx0) ? hy * hx * m : 0.f,
                             (vy0 && vx1) ? hy * lx * m : 0.f,
                             (vy1 && vx0) ? ly * hx * m : 0.f,
                             (vy1 && vx1) ? ly * lx * m : 0.f);
  }
  const int cog = tid >> 4, pg = tid & 15;
  float acc[8][4];
#pragma unroll
  for (int j = 0; j < 8; ++j)
#pragma unroll
    for (int q = 0; q < 4; ++q) acc[j][q] = 0.f;
  const float* inp_b = input + (size_t)b * CIN * HW;
  for (int k = 0; k < KK; ++k) {
    for (int cc = 0; cc < 2; ++cc) {
      __syncthreads();
      for (int i = tid; i < 64 * 64; i += 256) {
        const int cil = i >> 6, pp = i & 63;
        const float* plane = inp_b + (size_t)(cc * 64 + cil) * HW;
        const short4 o = pos_o[k * 64 + pp];
        const float4 w = pos_w[k * 64 + pp];
        s_tile[i] = w.x * plane[(int)o.x] + w.y * plane[(int)o.y] +
                    w.z * plane[(int)o.z] + w.w * plane[(int)o.w];
      }
      for (int i = tid; i < 64 * 128; i += 256) {
        const int cil = i & 63, co = i >> 6;
        w_tile[cil * 128 + co] = weight[(co * CIN + cc * 64 + cil) * KK + k];
      }
      __syncthreads();
#pragma unroll 8
      for (int cil = 0; cil < 64; ++cil) {
        const float4 sv = *(const float4*)&s_tile[cil * 64 + (pg << 2)];
        const float4 wa = *(const float4*)&w_tile[cil * 128 + (cog << 3)];
        const float4 wb = *(const float4*)&w_tile[cil * 128 + (cog << 3) + 4];
        const float s4[4] = {sv.x, sv.y, sv.z, sv.w};
        const float w8[8] = {wa.x, wa.y, wa.z, wa.w, wb.x, wb.y, wb.z, wb.w};
#pragma unroll
        for (int j = 0; j < 8; ++j)
#pragma unroll
          for (int q = 0; q < 4; ++q) acc[j][q] = fmaf(w8[j], s4[q], acc[j][q]);
      }
    }
  }
  float* outp = out + (size_t)b * COUT * HW + ho * W;
#pragma unroll
  for (int j = 0; j < 8; ++j) {
    const int co = (cog << 3) + j;
    const float bb = bias[co];
    *(float4*)&outp[co * HW + (pg << 2)] =
        make_float4(acc[j][0] + bb, acc[j][1] + bb, acc[j][2] + bb,
                    acc[j][3] + bb);
  }
}

extern "C" void kernel_launch(void* const* d_in, const int* in_sizes, int n_in,
                              void* d_out, int out_size, void* d_ws,
                              size_t ws_size, hipStream_t stream) {
  const float* input = (const float*)d_in[0];
  const float* offset = (const float*)d_in[1];
  const float* mask = (const float*)d_in[2];
  const float* weight = (const float*)d_in[3];
  const float* bias = (const float*)d_in[4];
  float* out = (float*)d_out;

  const size_t wt_elems = 36 * 8 * 64 * 8;  // 147456 bf16
  if (ws_size >= wt_elems * sizeof(unsigned short)) {
    unsigned short* wt = (unsigned short*)d_ws;
    hipLaunchKernelGGL(wprep_kernel, dim3(72), dim3(256), 0, stream, weight, wt);
    hipLaunchKernelGGL(dcn_mfma_kernel, dim3(1024), dim3(256), 0, stream, input,
                       offset, mask, wt, bias, out);
  } else {
    hipLaunchKernelGGL(dcn_fp32_kernel, dim3(512), dim3(256), 0, stream, input,
                       offset, mask, weight, bias, out);
  }
}

// Round 5
// 105.910 us; speedup vs baseline: 2.4145x; 1.5423x over previous
//
#include <hip/hip_runtime.h>

// DCNv2 fused, round 5: channels-last bf16 gather + MFMA.
// B=8, Cin=Cout=128, H=W=Ho=Wo=64, kh=kw=3, stride=1, pad=1, dil=1.
//
// R4 diagnosis: per-lane-divergent gathers (each wave-load touching ~30-60
// cache lines) saturate the L1/TA port (~100M line transactions). Fix:
// pre-transpose input to channels-last bf16 inT[b][y][x][ci] so one tap
// position = 256 B contiguous; gathers become coalesced dwordx4 (~20x fewer
// L1 transactions, 295 MB total).
//
// grid 1024 = (ph, ho, b): b = blk&7 (XCD swizzle), ho = (blk>>3)&63,
// ph = blk>>9 (p-half). Block = 512 thr = 8 waves; block tile 128co x 32p,
// wave w: co 16w..16w+15 (2 ns x 4 ksub = 8 MFMA 16x16x32 per k-step).
// K-loop: 9 steps of K=128. Per step: convert+stage s_tile[buf] (bf16,
// pad-136 rows) -> barrier (nothing outstanding: free drain) -> A-frags from
// global (before gathers: FIFO vmcnt keeps prefetch alive) -> prefetch next
// gathers (4 dwordx4, 16 VGPRs) -> ds_read B + 8 MFMA.

constexpr int CIN = 128, COUT = 128, H = 64, W = 64, KK = 9;
constexpr int HW = H * W;
constexpr int SROW = 136;  // s_tile row stride (bf16 elems): 128 + 8 pad

typedef __attribute__((ext_vector_type(8))) short short8;
typedef __attribute__((ext_vector_type(4))) float float4v;

static __device__ __forceinline__ unsigned short f32_to_bf16_rne(float f) {
  unsigned u = __float_as_uint(f);
  return (unsigned short)((u + 0x7FFFu + ((u >> 16) & 1u)) >> 16);
}
static __device__ __forceinline__ float blo(unsigned u) {
  return __uint_as_float(u << 16);
}
static __device__ __forceinline__ float bhi(unsigned u) {
  return __uint_as_float(u & 0xFFFF0000u);
}

// ---- transpose prep: input[b][ci][y][x] f32 -> inT[b][y][x][ci] bf16 ----
__global__ __launch_bounds__(256) void tprep_kernel(
    const float* __restrict__ in, unsigned short* __restrict__ inT) {
  __shared__ unsigned short lt[64 * 130];  // [x][ci], pad 130
  const int b = blockIdx.x >> 6, y = blockIdx.x & 63;
  for (int i = threadIdx.x; i < 128 * 64; i += 256) {
    const int ci = i >> 6, x = i & 63;  // consecutive i -> consecutive x
    lt[x * 130 + ci] = f32_to_bf16_rne(in[((b * 128 + ci) * 64 + y) * 64 + x]);
  }
  __syncthreads();
  unsigned* outp = (unsigned*)inT + (size_t)(b * 64 + y) * 64 * 64;
  for (int i = threadIdx.x; i < 64 * 64; i += 256) {
    const int x = i >> 6, c2 = (i & 63) * 2;  // consecutive i -> consecutive ci
    outp[x * 64 + (i & 63)] =
        (unsigned)lt[x * 130 + c2] | ((unsigned)lt[x * 130 + c2 + 1] << 16);
  }
}

// ---- weight prep: w[co][ci][k] fp32 -> bf16 A-fragments ----
// wt[(k*4+ks)*8 + c16][lane][j]; value = w[co=c16*16+(lane&15)]
//                                         [ci=ks*32+(lane>>4)*8+j][k]
__global__ __launch_bounds__(256) void wprep_kernel(
    const float* __restrict__ w, unsigned short* __restrict__ wt) {
  const int t = blockIdx.x * 256 + threadIdx.x;
  if (t >= 9 * 4 * 8 * 64) return;
  const int lane = t & 63, c16 = (t >> 6) & 7, kt = t >> 9;
  const int ks = kt & 3, k = kt >> 2;
  const int co = c16 * 16 + (lane & 15);
  const int ci0 = ks * 32 + (lane >> 4) * 8;
  unsigned pk[4];
#pragma unroll
  for (int jj = 0; jj < 4; ++jj) {
    const unsigned short h0 =
        f32_to_bf16_rne(w[(co * CIN + ci0 + 2 * jj) * KK + k]);
    const unsigned short h1 =
        f32_to_bf16_rne(w[(co * CIN + ci0 + 2 * jj + 1) * KK + k]);
    pk[jj] = (unsigned)h0 | ((unsigned)h1 << 16);
  }
  *(uint4*)(wt + (size_t)t * 8) = make_uint4(pk[0], pk[1], pk[2], pk[3]);
}

__global__ __launch_bounds__(512, 8) void dcn_mfma_kernel(
    const unsigned short* __restrict__ inT, const float* __restrict__ offset,
    const float* __restrict__ mask, const unsigned short* __restrict__ wt,
    const float* __restrict__ bias, float* __restrict__ out) {
  __shared__ int2 pos_i[KK * 32];    // channel-last elem base: row0, row1
  __shared__ float4 pos_w[KK * 32];  // folded slot weights cA0,cB0,cA1,cB1
  __shared__ unsigned short s_t[2][32 * SROW];  // double-buffered [p][ci]

  const int b = blockIdx.x & 7;  // XCD swizzle: batch b -> XCD b (L2 locality)
  const int ho = (blockIdx.x >> 3) & 63;
  const int ph = blockIdx.x >> 9;  // 0..1: p-half
  const int tid = threadIdx.x;

  // ---- Phase A: per-(k,p) tables; taps folded onto slots (bx, bx+1) ----
  if (tid < KK * 32) {
    const int k = tid >> 5, p = tid & 31;
    const int pg = ph * 32 + p;
    const int ky = k / 3, kx = k - 3 * ky;
    const float py = (float)(ho - 1 + ky) +
                     offset[((b * 18 + 2 * k) * 64 + ho) * 64 + pg];
    const float px = (float)(pg - 1 + kx) +
                     offset[((b * 18 + 2 * k + 1) * 64 + ho) * 64 + pg];
    const float m = mask[((b * 9 + k) * 64 + ho) * 64 + pg];
    const float y0f = floorf(py), x0f = floorf(px);
    const int y0 = (int)y0f, x0 = (int)x0f;
    const float ly = py - y0f, lx = px - x0f;
    const float hy = 1.f - ly, hx = 1.f - lx;
    const bool vy0 = (y0 >= 0) && (y0 < H);
    const bool vy1 = (y0 + 1 >= 0) && (y0 + 1 < H);
    const bool vx0 = (x0 >= 0) && (x0 < W);
    const bool vx1 = (x0 + 1 >= 0) && (x0 + 1 < W);
    const float w00 = (vy0 && vx0) ? hy * hx * m : 0.f;
    const float w01 = (vy0 && vx1) ? hy * lx * m : 0.f;
    const float w10 = (vy1 && vx0) ? ly * hx * m : 0.f;
    const float w11 = (vy1 && vx1) ? ly * lx * m : 0.f;
    const int cy0 = min(max(y0, 0), H - 1), cy1 = min(max(y0 + 1, 0), H - 1);
    const int bx = min(max(x0, 0), W - 2);
    const int s0 = min(max(x0 - bx, 0), 1);
    const int s1 = min(max(x0 + 1 - bx, 0), 1);
    // exact fold: invalid taps weigh 0; shared slots add a zero term
    const float cA0 = (s0 == 0 ? w00 : 0.f) + (s1 == 0 ? w01 : 0.f);
    const float cB0 = (s0 == 1 ? w00 : 0.f) + (s1 == 1 ? w01 : 0.f);
    const float cA1 = (s0 == 0 ? w10 : 0.f) + (s1 == 0 ? w11 : 0.f);
    const float cB1 = (s0 == 1 ? w10 : 0.f) + (s1 == 1 ? w11 : 0.f);
    pos_i[tid] = make_int2((cy0 * 64 + bx) * 128, (cy1 * 64 + bx) * 128);
    pos_w[tid] = make_float4(cA0, cB0, cA1, cB1);
  }
  __syncthreads();

  const int wave = tid >> 6;  // 0..7 -> co block of 16
  const int lane = tid & 63;
  const int quad = lane >> 4, l15 = lane & 15;
  const int p_loc = tid >> 4;  // 0..31: staged p row
  const int cg = tid & 15;     // ci granule of 8 (16 B)

  float4v acc0 = (float4v)(0.f), acc1 = (float4v)(0.f);

  const unsigned short* inb = inT + (size_t)b * HW * 128;

  // prologue: table + gathers for k=0
  int2 P = pos_i[p_loc];
  float4 Wc = pos_w[p_loc];
  uint4 g00, g01, g10, g11;
  {
    const unsigned short* a0 = inb + P.x + cg * 8;
    const unsigned short* a1 = inb + P.y + cg * 8;
    g00 = *(const uint4*)a0;
    g01 = *(const uint4*)(a0 + 128);
    g10 = *(const uint4*)a1;
    g11 = *(const uint4*)(a1 + 128);
  }

  for (int k = 0; k < KK; ++k) {
    const int buf = k & 1;
    // ---- convert + stage: s[ci] = cA0*v00 + cB0*v01 + cA1*v10 + cB1*v11 ----
    {
      const unsigned u00[4] = {g00.x, g00.y, g00.z, g00.w};
      const unsigned u01[4] = {g01.x, g01.y, g01.z, g01.w};
      const unsigned u10[4] = {g10.x, g10.y, g10.z, g10.w};
      const unsigned u11[4] = {g11.x, g11.y, g11.z, g11.w};
      unsigned pk[4];
#pragma unroll
      for (int j = 0; j < 4; ++j) {
        const float se = Wc.x * blo(u00[j]) + Wc.y * blo(u01[j]) +
                         Wc.z * blo(u10[j]) + Wc.w * blo(u11[j]);
        const float so = Wc.x * bhi(u00[j]) + Wc.y * bhi(u01[j]) +
                         Wc.z * bhi(u10[j]) + Wc.w * bhi(u11[j]);
        pk[j] = (unsigned)f32_to_bf16_rne(se) |
                ((unsigned)f32_to_bf16_rne(so) << 16);
      }
      *(uint4*)&s_t[buf][p_loc * SROW + cg * 8] =
          make_uint4(pk[0], pk[1], pk[2], pk[3]);
    }
    __syncthreads();  // nothing outstanding here: drain is free

    // ---- A-frags FIRST (FIFO: MFMA's vmcnt wait leaves gathers in flight) ----
    short8 A0, A1, A2, A3;
    {
      const unsigned short* wk =
          wt + ((size_t)(k * 4) * 8 + wave) * 512 + (size_t)lane * 8;
      A0 = *(const short8*)(wk);
      A1 = *(const short8*)(wk + 8 * 512);
      A2 = *(const short8*)(wk + 16 * 512);
      A3 = *(const short8*)(wk + 24 * 512);
    }

    // ---- prefetch next k's gathers (hidden under ds_read + MFMA) ----
    if (k < KK - 1) {
      P = pos_i[(k + 1) * 32 + p_loc];
      Wc = pos_w[(k + 1) * 32 + p_loc];
      const unsigned short* a0 = inb + P.x + cg * 8;
      const unsigned short* a1 = inb + P.y + cg * 8;
      g00 = *(const uint4*)a0;
      g01 = *(const uint4*)(a0 + 128);
      g10 = *(const uint4*)a1;
      g11 = *(const uint4*)(a1 + 128);
    }

    // ---- B ds_reads + 8 MFMA ----
#pragma unroll
    for (int ks = 0; ks < 4; ++ks) {
      const int col = ks * 32 + quad * 8;
      const short8 b0 = *(const short8*)&s_t[buf][l15 * SROW + col];
      const short8 b1 = *(const short8*)&s_t[buf][(16 + l15) * SROW + col];
      const short8 Ak = (ks == 0) ? A0 : (ks == 1) ? A1 : (ks == 2) ? A2 : A3;
      acc0 = __builtin_amdgcn_mfma_f32_16x16x32_bf16(Ak, b0, acc0, 0, 0, 0);
      acc1 = __builtin_amdgcn_mfma_f32_16x16x32_bf16(Ak, b1, acc1, 0, 0, 0);
    }
  }

  // ---- epilogue: C/D layout col(N=p)=lane&15, row(M=co)=quad*4+reg ----
#pragma unroll
  for (int r = 0; r < 4; ++r) {
    const int co = wave * 16 + quad * 4 + r;
    const float bb = bias[co];
    float* op = out + ((size_t)(b * COUT + co) * H + ho) * W + ph * 32;
    op[l15] = acc0[r] + bb;       // ns=0
    op[16 + l15] = acc1[r] + bb;  // ns=1
  }
}

// ---- fallback (ws too small): round-1 fp32 kernel ----
__global__ __launch_bounds__(256) void dcn_fp32_kernel(
    const float* __restrict__ input, const float* __restrict__ offset,
    const float* __restrict__ mask, const float* __restrict__ weight,
    const float* __restrict__ bias, float* __restrict__ out) {
  __shared__ short4 pos_o[KK * 64];
  __shared__ float4 pos_w[KK * 64];
  __shared__ float s_tile[64 * 64];
  __shared__ float w_tile[64 * 128];
  const int b = blockIdx.x >> 6;
  const int ho = blockIdx.x & 63;
  const int tid = threadIdx.x;
  for (int idx = tid; idx < KK * 64; idx += 256) {
    const int k = idx >> 6, pp = idx & 63;
    const int ky = k / 3, kx = k - 3 * ky;
    const float py = (float)(ho - 1 + ky) +
                     offset[((b * 18 + 2 * k) * 64 + ho) * 64 + pp];
    const float px = (float)(pp - 1 + kx) +
                     offset[((b * 18 + 2 * k + 1) * 64 + ho) * 64 + pp];
    const float m = mask[((b * 9 + k) * 64 + ho) * 64 + pp];
    const float y0f = floorf(py), x0f = floorf(px);
    const int y0 = (int)y0f, x0 = (int)x0f;
    const float ly = py - y0f, lx = px - x0f;
    const float hy = 1.f - ly, hx = 1.f - lx;
    const bool vy0 = (y0 >= 0) && (y0 < H), vy1 = (y0 + 1 >= 0) && (y0 + 1 < H);
    const bool vx0 = (x0 >= 0) && (x0 < W), vx1 = (x0 + 1 >= 0) && (x0 + 1 < W);
    const int cy0 = min(max(y0, 0), H - 1), cy1 = min(max(y0 + 1, 0), H - 1);
    const int cx0 = min(max(x0, 0), W - 1), cx1 = min(max(x0 + 1, 0), W - 1);
    pos_o[idx] = make_short4((short)(cy0 * W + cx0), (short)(cy0 * W + cx1),
                             (short)(cy1 * W + cx0), (short)(cy1 * W + cx1));
    pos_w[idx] = make_float4((vy0 && vx0) ? hy * hx * m : 0.f,
                             (vy0 && vx1) ? hy * lx * m : 0.f,
                             (vy1 && vx0) ? ly * hx * m : 0.f,
                             (vy1 && vx1) ? ly * lx * m : 0.f);
  }
  const int cog = tid >> 4, pg = tid & 15;
  float acc[8][4];
#pragma unroll
  for (int j = 0; j < 8; ++j)
#pragma unroll
    for (int q = 0; q < 4; ++q) acc[j][q] = 0.f;
  const float* inp_b = input + (size_t)b * CIN * HW;
  for (int k = 0; k < KK; ++k) {
    for (int cc = 0; cc < 2; ++cc) {
      __syncthreads();
      for (int i = tid; i < 64 * 64; i += 256) {
        const int cil = i >> 6, pp = i & 63;
        const float* plane = inp_b + (size_t)(cc * 64 + cil) * HW;
        const short4 o = pos_o[k * 64 + pp];
        const float4 w = pos_w[k * 64 + pp];
        s_tile[i] = w.x * plane[(int)o.x] + w.y * plane[(int)o.y] +
                    w.z * plane[(int)o.z] + w.w * plane[(int)o.w];
      }
      for (int i = tid; i < 64 * 128; i += 256) {
        const int cil = i & 63, co = i >> 6;
        w_tile[cil * 128 + co] = weight[(co * CIN + cc * 64 + cil) * KK + k];
      }
      __syncthreads();
#pragma unroll 8
      for (int cil = 0; cil < 64; ++cil) {
        const float4 sv = *(const float4*)&s_tile[cil * 64 + (pg << 2)];
        const float4 wa = *(const float4*)&w_tile[cil * 128 + (cog << 3)];
        const float4 wb = *(const float4*)&w_tile[cil * 128 + (cog << 3) + 4];
        const float s4[4] = {sv.x, sv.y, sv.z, sv.w};
        const float w8[8] = {wa.x, wa.y, wa.z, wa.w, wb.x, wb.y, wb.z, wb.w};
#pragma unroll
        for (int j = 0; j < 8; ++j)
#pragma unroll
          for (int q = 0; q < 4; ++q) acc[j][q] = fmaf(w8[j], s4[q], acc[j][q]);
      }
    }
  }
  float* outp = out + (size_t)b * COUT * HW + ho * W;
#pragma unroll
  for (int j = 0; j < 8; ++j) {
    const int co = (cog << 3) + j;
    const float bb = bias[co];
    *(float4*)&outp[co * HW + (pg << 2)] =
        make_float4(acc[j][0] + bb, acc[j][1] + bb, acc[j][2] + bb,
                    acc[j][3] + bb);
  }
}

extern "C" void kernel_launch(void* const* d_in, const int* in_sizes, int n_in,
                              void* d_out, int out_size, void* d_ws,
                              size_t ws_size, hipStream_t stream) {
  const float* input = (const float*)d_in[0];
  const float* offset = (const float*)d_in[1];
  const float* mask = (const float*)d_in[2];
  const float* weight = (const float*)d_in[3];
  const float* bias = (const float*)d_in[4];
  float* out = (float*)d_out;

  const size_t wt_bytes = (size_t)9 * 4 * 8 * 64 * 8 * 2;      // 294912
  const size_t inT_bytes = (size_t)8 * HW * 128 * 2;           // 8388608
  if (ws_size >= wt_bytes + inT_bytes) {
    unsigned short* wt = (unsigned short*)d_ws;
    unsigned short* inT = (unsigned short*)((char*)d_ws + wt_bytes);
    hipLaunchKernelGGL(wprep_kernel, dim3(72), dim3(256), 0, stream, weight, wt);
    hipLaunchKernelGGL(tprep_kernel, dim3(512), dim3(256), 0, stream, input, inT);
    hipLaunchKernelGGL(dcn_mfma_kernel, dim3(1024), dim3(512), 0, stream, inT,
                       offset, mask, wt, bias, out);
  } else {
    hipLaunchKernelGGL(dcn_fp32_kernel, dim3(512), dim3(256), 0, stream, input,
                       offset, mask, weight, bias, out);
  }
}